// Round 11
// baseline (189.796 us; speedup 1.0000x reference)
//
#include <hip/hip_runtime.h>

#define DIM   1024
#define NG    8
#define NBLK  128
#define TPB   512                 // 8 waves/block
#define WAVES (TPB / 64)
#define RPW   1                   // rows per wave: NBLK*WAVES*RPW = 1024
#define ROWS_PER_BLK (WAVES * RPW)
#define SCALE    1.45f            // upper bound on spectral radius (semicircle ~1.414)
#define INVSCALE (1.0f / SCALE)
#define CTOL  5e-3f               // frozen: measured absmax 9.16e-5 vs 1.40e-4 threshold
#define KMAX  12
#define FSTRIDE 16                // flags padded to 64B (16 u32) each

typedef unsigned long long u64;
union f2u { float2 f; u64 u; };

// Mechanism: R7/R9/R10 verbatim. R11 attacks the ~30us in-kernel fixed term
// (cost model: t = ~3.1us * phases + fixed):
//  - NBLK 128 / RPW 1: per-CU G traffic halves (32KB/gate ~1.1us, fully
//    hidden in the one-phase prefetch window); 128 CUs share all fixed
//    work; per-wave FMA/butterfly halves.
//  - poll: 2 loads/lane over 128 padded single-writer flag lines (R6's
//    regression was SHARED multi-flag lines; these stay one-writer-per-line).
// Arithmetic order per row is unchanged -> absmax should be bit-identical.

__global__ __launch_bounds__(TPB) void qsim_kernel(
    const float* __restrict__ feat,
    const float* __restrict__ theta,
    const float* __restrict__ gens,
    float*       __restrict__ out,
    u64*         __restrict__ vbuf0,
    u64*         __restrict__ vbuf1,
    unsigned*    __restrict__ flags)
{
  const int tid  = threadIdx.x;
  const int lane = tid & 63;
  const int wid  = tid >> 6;                       // 0..7
  const int bid  = blockIdx.x;
  const int row  = bid * ROWS_PER_BLK + wid;       // one row per wave

  __shared__ float red[WAVES];
  __shared__ unsigned wdone;                       // monotone publish counter
  __shared__ unsigned ready;                       // monotone wake word

  // ---- gate-0 G row first: HBM latency overlaps the norm phase ----
  float a[16];
  {
    const float* Gr = gens + (size_t)row * DIM;
    #pragma unroll
    for (int p = 0; p < 16; ++p) a[p] = Gr[p * 64 + lane];
  }

  if (tid == 0) { wdone = 0; ready = 0; }
  {
    float f0 = feat[tid], f1 = feat[tid + TPB];
    float s = f0 * f0 + f1 * f1;
    #pragma unroll
    for (int mm = 1; mm < 64; mm <<= 1) s += __shfl_xor(s, mm);
    if (lane == 0) red[wid] = s;
  }
  __syncthreads();                                  // init only
  float tot = 0.f;
  #pragma unroll
  for (int i = 0; i < WAVES; ++i) tot += red[i];
  const float inv = 1.0f / sqrtf(tot);

  float pr = feat[row] * inv;
  float pi = 0.f;

  unsigned pub = 0;   // completed publishes (lock-stepped across all waves)

  auto publish = [&](float sr, float si) {
    u64* dst = ((pub + 1) & 1) ? vbuf1 : vbuf0;
    if (lane == 0) {
      f2u x; x.f = make_float2(sr, si);
      __hip_atomic_store(dst + row, x.u,
                         __ATOMIC_RELAXED, __HIP_MEMORY_SCOPE_AGENT);
    }
    __builtin_amdgcn_sched_barrier(0);
    __builtin_amdgcn_s_waitcnt(0);    // wave's data store at the LLC now
    __builtin_amdgcn_sched_barrier(0);
    ++pub;
    if (lane == 0) {
      unsigned old = atomicAdd(&wdone, 1u);         // LDS, monotone
      if (old == WAVES * pub - 1) {                 // block's last publisher
        __hip_atomic_store(flags + bid * FSTRIDE, pub,
                           __ATOMIC_RELEASE, __HIP_MEMORY_SCOPE_AGENT);
      }
    }
  };

  auto wait_all = [&]() {
    if (wid == 0) {
      for (;;) {
        unsigned f0 = __hip_atomic_load(flags + lane * FSTRIDE,
                                        __ATOMIC_RELAXED,
                                        __HIP_MEMORY_SCOPE_AGENT);
        unsigned f1 = __hip_atomic_load(flags + (lane + 64) * FSTRIDE,
                                        __ATOMIC_RELAXED,
                                        __HIP_MEMORY_SCOPE_AGENT);
        // wrap-safe monotone >=; 0xAAAAAAAA poison reads "not ready"
        if (__all(((int)(f0 - pub) >= 0) & ((int)(f1 - pub) >= 0))) break;
      }
      if (lane == 0)
        __hip_atomic_store(&ready, pub, __ATOMIC_RELAXED,
                           __HIP_MEMORY_SCOPE_WORKGROUP);
    } else {
      while ((int)(__hip_atomic_load(&ready, __ATOMIC_RELAXED,
                                     __HIP_MEMORY_SCOPE_WORKGROUP) - pub) < 0) {
      }
    }
  };

  for (int g = 0; g < NG; ++g) {
    // ---- Chebyshev coefficients: J_k(|z|), downward Miller in fp64 ----
    const float  th = theta[g];
    const double z  = (double)th * (double)SCALE;
    const double az = fmax(fabs(z), 1e-6);
    const float  sg = (th < 0.f) ? -1.f : 1.f;      // J_k(z)=sg^k J_k(|z|)

    double bv[19];
    bv[18] = 1e-30;
    bv[17] = (36.0 / az) * 1e-30;
    #pragma unroll
    for (int k = 17; k >= 1; --k)
      bv[k - 1] = (2.0 * (double)k / az) * bv[k] - bv[k + 1];
    double S = bv[0];
    #pragma unroll
    for (int k = 2; k <= 18; k += 2) S += 2.0 * bv[k];
    const double invS = 1.0 / S;

    // coeffs to float REGISTERS (constant indices only from here on)
    float jc[KMAX + 2];
    #pragma unroll
    for (int k = 0; k <= KMAX + 1; ++k) jc[k] = (float)(bv[k] * invS);

    int m = KMAX; bool found = false;
    #pragma unroll
    for (int k = 1; k <= KMAX; ++k) {
      if (!found && (double)(k + 1) > az &&
          fabs(bv[k + 1] * invS) < (double)CTOL) { m = k; found = true; }
    }
    // m identical on every wave/block -> uniform phase count

    float accr = jc[0] * pr, acci = jc[0] * pi;
    float wm1r = pr, wm1i = pi, wm2r = 0.f, wm2i = 0.f;

    #pragma unroll
    for (int k = 1; k <= KMAX; ++k) {               // fully unrolled
      if (k > m) break;

      // ---- consume full w_{k-1} ----
      float vr[16], vi[16];
      if (g == 0 && k == 1) {
        // psi_0 rebuilt locally: no publish/wait phase needed
        #pragma unroll
        for (int p = 0; p < 16; ++p) {
          vr[p] = feat[p * 64 + lane] * inv;
          vi[p] = 0.f;
        }
      } else {
        wait_all();
        const u64* vsrc = (pub & 1) ? vbuf1 : vbuf0;  // buffer of phase pub
        #pragma unroll
        for (int p = 0; p < 16; ++p) {
          f2u x;
          x.u = __hip_atomic_load(vsrc + p * 64 + lane,
                                  __ATOMIC_RELAXED, __HIP_MEMORY_SCOPE_AGENT);
          vr[p] = x.f.x; vi[p] = x.f.y;
        }
      }

      // ---- y = G * w_{k-1} (own row) ----
      float yr = 0.f, yi = 0.f;
      #pragma unroll
      for (int p = 0; p < 16; ++p) {
        yr = fmaf(a[p], vr[p], yr);
        yi = fmaf(a[p], vi[p], yi);
      }
      #pragma unroll
      for (int mm = 1; mm < 64; mm <<= 1) {
        yr += __shfl_xor(yr, mm);
        yi += __shfl_xor(yi, mm);
      }

      // ---- w_k = (k==1) ? xh*w_0 : 2*xh*w_{k-1} - w_{k-2} ----
      const float ur = yr * INVSCALE;
      const float ui = yi * INVSCALE;
      const float wkr = (k == 1) ? ur : fmaf(2.f, ur, -wm2r);
      const float wki = (k == 1) ? ui : fmaf(2.f, ui, -wm2i);

      const bool last = (k == m);
      if (!last) publish(wkr, wki);   // store flies before the tail VALU

      // ---- acc += c_k * w_k,  c_k = 2*(-i*sg)^k * J_k(|z|) ----
      {
        const float j2  = 2.f * jc[k];              // register (constant k)
        const float sj2 = sg * j2;
        if ((k & 3) == 0)      { accr = fmaf( j2,  wkr, accr); acci = fmaf( j2,  wki, acci); }
        else if ((k & 3) == 1) { accr = fmaf( sj2, wki, accr); acci = fmaf(-sj2, wkr, acci); }
        else if ((k & 3) == 2) { accr = fmaf(-j2,  wkr, accr); acci = fmaf(-j2,  wki, acci); }
        else                   { accr = fmaf(-sj2, wki, accr); acci = fmaf( sj2, wkr, acci); }
      }

      if (last) {
        if (g < NG - 1) {
          publish(accr, acci);                      // psi_{g+1}
          // next gate's G row; completes while the next wait_all spins
          const float* Gr = gens + ((size_t)(g + 1) * DIM + row) * DIM;
          #pragma unroll
          for (int p = 0; p < 16; ++p) a[p] = Gr[p * 64 + lane];
        }
      } else {
        wm2r = wm1r; wm2i = wm1i;
        wm1r = wkr;  wm1i = wki;
      }
    }
    pr = accr; pi = acci;
  }

  if (lane == 0) out[row] = pr * pr + pi * pi;
}

extern "C" void kernel_launch(void* const* d_in, const int* in_sizes, int n_in,
                              void* d_out, int out_size, void* d_ws, size_t ws_size,
                              hipStream_t stream) {
  const float* feat  = (const float*)d_in[0];
  const float* theta = (const float*)d_in[1];
  const float* gens  = (const float*)d_in[2];
  float* out = (float*)d_out;

  // layout: flags 128 x 64B (8KB) | vbuf0 (8KB) | vbuf1 (8KB)
  // no memset: wrap-safe compare treats the 0xAA poison as "not ready"
  unsigned* flags = (unsigned*)d_ws;
  u64* vbuf0 = (u64*)((char*)d_ws + 8192);
  u64* vbuf1 = (u64*)((char*)d_ws + 8192 + DIM * sizeof(u64));

  qsim_kernel<<<dim3(NBLK), dim3(TPB), 0, stream>>>(
      feat, theta, gens, out, vbuf0, vbuf1, flags);
}

// Round 12
// 170.411 us; speedup vs baseline: 1.1138x; 1.1138x over previous
//
#include <hip/hip_runtime.h>

#define DIM   1024
#define NG    8
#define NBLK  64
#define TPB   512                 // 8 waves/block
#define WAVES (TPB / 64)
#define RPW   2                   // rows per wave: NBLK*WAVES*RPW = 1024
#define ROWS_PER_BLK (WAVES * RPW)
#define SCALE    1.45f            // upper bound on spectral radius (semicircle ~1.414)
#define INVSCALE (1.0f / SCALE)
#define CTOL  5e-3f               // frozen: measured absmax 9.16e-5 vs 1.40e-4 threshold
#define KMAX  12
#define FSTRIDE 16                // flags padded to 64B (16 u32) each

typedef unsigned long long u64;
union f2u { float2 f; u64 u; };

// Mechanism: R10 verbatim (measured optimum: 64 blocks, ~3.2us/phase).
// R12 change: SMOOTHED G prefetch. R10 issued the next gate's 64KB G rows
// as one burst at the gate boundary; vmcnt is strictly ordered, so those
// outstanding loads drain into wave0's first poll and the k=1 consume
// (~1us exposed per gate). Now the prefetch is split into 4 chunks of 8
// loads (~0.7us each), chunk k-1 issued right after publish(w_k) -- each
// hides fully inside its ~3us phase window. Remainder chunks (short gates,
// m<5) issue at the gate boundary as before. The staged rows land in b[][]
// and are copied to a[][] after the NEXT gate's Miller recurrence, so the
// residual waitcnt sits ~1us after issue. Per-row arithmetic unchanged ->
// absmax must be bit-identical to R10 (9.155273e-05).

__global__ __launch_bounds__(TPB) void qsim_kernel(
    const float* __restrict__ feat,
    const float* __restrict__ theta,
    const float* __restrict__ gens,
    float*       __restrict__ out,
    u64*         __restrict__ vbuf0,
    u64*         __restrict__ vbuf1,
    unsigned*    __restrict__ flags)
{
  const int tid  = threadIdx.x;
  const int lane = tid & 63;
  const int wid  = tid >> 6;                       // 0..7
  const int bid  = blockIdx.x;
  const int rowbase = bid * ROWS_PER_BLK + wid * RPW;

  __shared__ float red[WAVES];
  __shared__ unsigned wdone;                       // monotone publish counter
  __shared__ unsigned ready;                       // monotone wake word

  // ---- gate-0 G rows first: HBM latency overlaps the norm phase ----
  float a[RPW][16];                                // current gate rows
  float b[RPW][16];                                // next-gate staging
  #pragma unroll
  for (int rr = 0; rr < RPW; ++rr) {
    const float* Gr = gens + (size_t)(rowbase + rr) * DIM;
    #pragma unroll
    for (int p = 0; p < 16; ++p) a[rr][p] = Gr[p * 64 + lane];
  }

  if (tid == 0) { wdone = 0; ready = 0; }
  {
    float f0 = feat[tid], f1 = feat[tid + TPB];
    float s = f0 * f0 + f1 * f1;
    #pragma unroll
    for (int mm = 1; mm < 64; mm <<= 1) s += __shfl_xor(s, mm);
    if (lane == 0) red[wid] = s;
  }
  __syncthreads();                                  // init only
  float tot = 0.f;
  #pragma unroll
  for (int i = 0; i < WAVES; ++i) tot += red[i];
  const float inv = 1.0f / sqrtf(tot);

  float pr[RPW], pi[RPW];
  #pragma unroll
  for (int rr = 0; rr < RPW; ++rr) {
    pr[rr] = feat[rowbase + rr] * inv;
    pi[rr] = 0.f;
  }

  unsigned pub = 0;   // completed publishes (lock-stepped across all waves)

  auto publish = [&](const float* xr, const float* xi) {
    float sr = xr[0], si = xi[0];
    if (lane == 1) { sr = xr[1]; si = xi[1]; }
    u64* dst = ((pub + 1) & 1) ? vbuf1 : vbuf0;
    if (lane < RPW) {
      f2u x; x.f = make_float2(sr, si);
      __hip_atomic_store(dst + rowbase + lane, x.u,
                         __ATOMIC_RELAXED, __HIP_MEMORY_SCOPE_AGENT);
    }
    __builtin_amdgcn_sched_barrier(0);
    __builtin_amdgcn_s_waitcnt(0);    // wave's data stores at the LLC now
    __builtin_amdgcn_sched_barrier(0);
    ++pub;
    if (lane == 0) {
      unsigned old = atomicAdd(&wdone, 1u);         // LDS, monotone
      if (old == WAVES * pub - 1) {                 // block's last publisher
        __hip_atomic_store(flags + bid * FSTRIDE, pub,
                           __ATOMIC_RELEASE, __HIP_MEMORY_SCOPE_AGENT);
      }
    }
  };

  auto wait_all = [&]() {
    if (wid == 0) {
      for (;;) {
        unsigned f = __hip_atomic_load(flags + lane * FSTRIDE,
                                       __ATOMIC_RELAXED,
                                       __HIP_MEMORY_SCOPE_AGENT);
        // wrap-safe monotone >=; 0xAAAAAAAA poison reads "not ready"
        if (__all((int)(f - pub) >= 0)) break;
      }
      if (lane == 0)
        __hip_atomic_store(&ready, pub, __ATOMIC_RELAXED,
                           __HIP_MEMORY_SCOPE_WORKGROUP);
    } else {
      while ((int)(__hip_atomic_load(&ready, __ATOMIC_RELAXED,
                                     __HIP_MEMORY_SCOPE_WORKGROUP) - pub) < 0) {
      }
    }
  };

  for (int g = 0; g < NG; ++g) {
    // ---- Chebyshev coefficients: J_k(|z|), downward Miller in fp64 ----
    const float  th = theta[g];
    const double z  = (double)th * (double)SCALE;
    const double az = fmax(fabs(z), 1e-6);
    const float  sg = (th < 0.f) ? -1.f : 1.f;      // J_k(z)=sg^k J_k(|z|)

    double bv[19];
    bv[18] = 1e-30;
    bv[17] = (36.0 / az) * 1e-30;
    #pragma unroll
    for (int k = 17; k >= 1; --k)
      bv[k - 1] = (2.0 * (double)k / az) * bv[k] - bv[k + 1];
    double S = bv[0];
    #pragma unroll
    for (int k = 2; k <= 18; k += 2) S += 2.0 * bv[k];
    const double invS = 1.0 / S;

    // coeffs to float REGISTERS (constant indices only from here on)
    float jc[KMAX + 2];
    #pragma unroll
    for (int k = 0; k <= KMAX + 1; ++k) jc[k] = (float)(bv[k] * invS);

    int m = KMAX; bool found = false;
    #pragma unroll
    for (int k = 1; k <= KMAX; ++k) {
      if (!found && (double)(k + 1) > az &&
          fabs(bv[k + 1] * invS) < (double)CTOL) { m = k; found = true; }
    }
    // m identical on every wave/block -> uniform phase count

    // ---- adopt prefetched rows (staged during the previous gate) ----
    if (g > 0) {
      #pragma unroll
      for (int rr = 0; rr < RPW; ++rr)
        #pragma unroll
        for (int p = 0; p < 16; ++p) a[rr][p] = b[rr][p];
    }

    const float* Gnext = gens + (size_t)(g + 1) * DIM * DIM;

    float accr[RPW], acci[RPW];
    float wm1r[RPW], wm1i[RPW], wm2r[RPW], wm2i[RPW];
    #pragma unroll
    for (int rr = 0; rr < RPW; ++rr) {
      accr[rr] = jc[0] * pr[rr]; acci[rr] = jc[0] * pi[rr];
      wm1r[rr] = pr[rr];         wm1i[rr] = pi[rr];
      wm2r[rr] = 0.f;            wm2i[rr] = 0.f;
    }

    #pragma unroll
    for (int k = 1; k <= KMAX; ++k) {               // fully unrolled
      if (k > m) break;

      // ---- consume full w_{k-1} ----
      float vr[16], vi[16];
      if (g == 0 && k == 1) {
        // psi_0 rebuilt locally: no publish/wait phase needed
        #pragma unroll
        for (int p = 0; p < 16; ++p) {
          vr[p] = feat[p * 64 + lane] * inv;
          vi[p] = 0.f;
        }
      } else {
        wait_all();
        const u64* vsrc = (pub & 1) ? vbuf1 : vbuf0;  // buffer of phase pub
        #pragma unroll
        for (int p = 0; p < 16; ++p) {
          f2u x;
          x.u = __hip_atomic_load(vsrc + p * 64 + lane,
                                  __ATOMIC_RELAXED, __HIP_MEMORY_SCOPE_AGENT);
          vr[p] = x.f.x; vi[p] = x.f.y;
        }
      }

      // ---- y = G * w_{k-1} (own rows) ----
      float yr[RPW] = {0, 0}, yi[RPW] = {0, 0};
      #pragma unroll
      for (int p = 0; p < 16; ++p) {
        #pragma unroll
        for (int rr = 0; rr < RPW; ++rr) {
          yr[rr] = fmaf(a[rr][p], vr[p], yr[rr]);
          yi[rr] = fmaf(a[rr][p], vi[p], yi[rr]);
        }
      }
      #pragma unroll
      for (int mm = 1; mm < 64; mm <<= 1) {
        #pragma unroll
        for (int rr = 0; rr < RPW; ++rr) {
          yr[rr] += __shfl_xor(yr[rr], mm);
          yi[rr] += __shfl_xor(yi[rr], mm);
        }
      }

      // ---- w_k = (k==1) ? xh*w_0 : 2*xh*w_{k-1} - w_{k-2}  (own rows) ----
      float wkr[RPW], wki[RPW];
      #pragma unroll
      for (int rr = 0; rr < RPW; ++rr) {
        const float ur = yr[rr] * INVSCALE;
        const float ui = yi[rr] * INVSCALE;
        wkr[rr] = (k == 1) ? ur : fmaf(2.f, ur, -wm2r[rr]);
        wki[rr] = (k == 1) ? ui : fmaf(2.f, ui, -wm2i[rr]);
      }

      const bool last = (k == m);
      if (!last) {
        publish(wkr, wki);            // stores fly before the tail VALU below
        // smoothed prefetch: chunk k-1 (8 loads, ~0.7us) hides in this
        // phase window; next publish's waitcnt lands ~3us later.
        if (k <= 4 && g + 1 < NG) {
          #pragma unroll
          for (int rr = 0; rr < RPW; ++rr) {
            const float* Gr = Gnext + (size_t)(rowbase + rr) * DIM;
            #pragma unroll
            for (int j = 0; j < 4; ++j)
              b[rr][(k - 1) * 4 + j] = Gr[((k - 1) * 4 + j) * 64 + lane];
          }
        }
      }

      // ---- acc += c_k * w_k,  c_k = 2*(-i*sg)^k * J_k(|z|) ----
      {
        const float j2  = 2.f * jc[k];              // register (constant k)
        const float sj2 = sg * j2;
        if ((k & 3) == 0) {
          #pragma unroll
          for (int rr = 0; rr < RPW; ++rr) {
            accr[rr] = fmaf(j2, wkr[rr], accr[rr]);
            acci[rr] = fmaf(j2, wki[rr], acci[rr]);
          }
        } else if ((k & 3) == 1) {
          #pragma unroll
          for (int rr = 0; rr < RPW; ++rr) {
            accr[rr] = fmaf( sj2, wki[rr], accr[rr]);
            acci[rr] = fmaf(-sj2, wkr[rr], acci[rr]);
          }
        } else if ((k & 3) == 2) {
          #pragma unroll
          for (int rr = 0; rr < RPW; ++rr) {
            accr[rr] = fmaf(-j2, wkr[rr], accr[rr]);
            acci[rr] = fmaf(-j2, wki[rr], acci[rr]);
          }
        } else {
          #pragma unroll
          for (int rr = 0; rr < RPW; ++rr) {
            accr[rr] = fmaf(-sj2, wki[rr], accr[rr]);
            acci[rr] = fmaf( sj2, wkr[rr], acci[rr]);
          }
        }
      }

      if (last) {
        if (g < NG - 1) {
          publish(accr, acci);                      // psi_{g+1}
          // remainder chunks (c >= m-1): only short gates reach here with
          // work left; they drain during the next wait_all window.
          #pragma unroll
          for (int c = 0; c < 4; ++c) {
            if (c + 1 >= m) {
              #pragma unroll
              for (int rr = 0; rr < RPW; ++rr) {
                const float* Gr = Gnext + (size_t)(rowbase + rr) * DIM;
                #pragma unroll
                for (int j = 0; j < 4; ++j)
                  b[rr][c * 4 + j] = Gr[(c * 4 + j) * 64 + lane];
              }
            }
          }
        }
      } else {
        #pragma unroll
        for (int rr = 0; rr < RPW; ++rr) {
          wm2r[rr] = wm1r[rr]; wm2i[rr] = wm1i[rr];
          wm1r[rr] = wkr[rr];  wm1i[rr] = wki[rr];
        }
      }
    }
    #pragma unroll
    for (int rr = 0; rr < RPW; ++rr) { pr[rr] = accr[rr]; pi[rr] = acci[rr]; }
  }

  {
    float o = pr[0] * pr[0] + pi[0] * pi[0];
    if (lane == 1) o = pr[1] * pr[1] + pi[1] * pi[1];
    if (lane < RPW) out[rowbase + lane] = o;
  }
}

extern "C" void kernel_launch(void* const* d_in, const int* in_sizes, int n_in,
                              void* d_out, int out_size, void* d_ws, size_t ws_size,
                              hipStream_t stream) {
  const float* feat  = (const float*)d_in[0];
  const float* theta = (const float*)d_in[1];
  const float* gens  = (const float*)d_in[2];
  float* out = (float*)d_out;

  // layout: flags 64 x 64B (4KB) | vbuf0 (8KB) | vbuf1 (8KB)
  // no memset: wrap-safe compare treats the 0xAA poison as "not ready"
  unsigned* flags = (unsigned*)d_ws;
  u64* vbuf0 = (u64*)((char*)d_ws + 4096);
  u64* vbuf1 = (u64*)((char*)d_ws + 4096 + DIM * sizeof(u64));

  qsim_kernel<<<dim3(NBLK), dim3(TPB), 0, stream>>>(
      feat, theta, gens, out, vbuf0, vbuf1, flags);
}

// Round 13
// 166.797 us; speedup vs baseline: 1.1379x; 1.0217x over previous
//
#include <hip/hip_runtime.h>

#define DIM   1024
#define NG    8
#define NBLK  64
#define TPB   256                 // 4 waves/block (lockstep population halved)
#define WAVES (TPB / 64)
#define RPW   4                   // rows per wave: NBLK*WAVES*RPW = 1024
#define ROWS_PER_BLK (WAVES * RPW)
#define SCALE    1.45f            // upper bound on spectral radius (semicircle ~1.414)
#define INVSCALE (1.0f / SCALE)
#define CTOL  5e-3f               // frozen: measured absmax 9.16e-5 vs 1.40e-4 threshold
#define KMAX  12
#define FSTRIDE 16                // flags padded to 64B (16 u32) each

typedef unsigned long long u64;
union f2u { float2 f; u64 u; };

// Mechanism: R10 verbatim except TPB 512->256 (RPW 2->4).
// Rationale (R12 post-mortem): every phase waits on max over all lockstep
// waves; halving the population (512->256) and the per-block LDS-atomic
// serial depth (8->4) trims the arrival tail without touching the
// measured-optimal NBLK=64 / flag / poll structure. Per-row arithmetic is
// unchanged -> absmax must stay bit-identical (9.155273e-05).
// R12 lesson kept: NO vmem between publish and the next consume except the
// once-per-gate boundary burst, which drains inside the wait_all spin.

__global__ __launch_bounds__(TPB) void qsim_kernel(
    const float* __restrict__ feat,
    const float* __restrict__ theta,
    const float* __restrict__ gens,
    float*       __restrict__ out,
    u64*         __restrict__ vbuf0,
    u64*         __restrict__ vbuf1,
    unsigned*    __restrict__ flags)
{
  const int tid  = threadIdx.x;
  const int lane = tid & 63;
  const int wid  = tid >> 6;                       // 0..3
  const int bid  = blockIdx.x;
  const int rowbase = bid * ROWS_PER_BLK + wid * RPW;

  __shared__ float red[WAVES];
  __shared__ unsigned wdone;                       // monotone publish counter
  __shared__ unsigned ready;                       // monotone wake word

  // ---- gate-0 G rows first: HBM latency overlaps the norm phase ----
  float a[RPW][16];
  #pragma unroll
  for (int rr = 0; rr < RPW; ++rr) {
    const float* Gr = gens + (size_t)(rowbase + rr) * DIM;
    #pragma unroll
    for (int p = 0; p < 16; ++p) a[rr][p] = Gr[p * 64 + lane];
  }

  if (tid == 0) { wdone = 0; ready = 0; }
  {
    float f0 = feat[tid],       f1 = feat[tid + TPB];
    float f2 = feat[tid + 512], f3 = feat[tid + 768];
    float s = f0 * f0 + f1 * f1 + f2 * f2 + f3 * f3;
    #pragma unroll
    for (int mm = 1; mm < 64; mm <<= 1) s += __shfl_xor(s, mm);
    if (lane == 0) red[wid] = s;
  }
  __syncthreads();                                  // init only
  float tot = 0.f;
  #pragma unroll
  for (int i = 0; i < WAVES; ++i) tot += red[i];
  const float inv = 1.0f / sqrtf(tot);

  float pr[RPW], pi[RPW];
  #pragma unroll
  for (int rr = 0; rr < RPW; ++rr) {
    pr[rr] = feat[rowbase + rr] * inv;
    pi[rr] = 0.f;
  }

  unsigned pub = 0;   // completed publishes (lock-stepped across all waves)

  auto publish = [&](const float* xr, const float* xi) {
    float sr = xr[0], si = xi[0];
    if (lane == 1) { sr = xr[1]; si = xi[1]; }
    if (lane == 2) { sr = xr[2]; si = xi[2]; }
    if (lane == 3) { sr = xr[3]; si = xi[3]; }
    u64* dst = ((pub + 1) & 1) ? vbuf1 : vbuf0;
    if (lane < RPW) {
      f2u x; x.f = make_float2(sr, si);
      __hip_atomic_store(dst + rowbase + lane, x.u,
                         __ATOMIC_RELAXED, __HIP_MEMORY_SCOPE_AGENT);
    }
    __builtin_amdgcn_sched_barrier(0);
    __builtin_amdgcn_s_waitcnt(0);    // wave's data stores at the LLC now
    __builtin_amdgcn_sched_barrier(0);
    ++pub;
    if (lane == 0) {
      unsigned old = atomicAdd(&wdone, 1u);         // LDS, monotone
      if (old == WAVES * pub - 1) {                 // block's last publisher
        __hip_atomic_store(flags + bid * FSTRIDE, pub,
                           __ATOMIC_RELEASE, __HIP_MEMORY_SCOPE_AGENT);
      }
    }
  };

  auto wait_all = [&]() {
    if (wid == 0) {
      for (;;) {
        unsigned f = __hip_atomic_load(flags + lane * FSTRIDE,
                                       __ATOMIC_RELAXED,
                                       __HIP_MEMORY_SCOPE_AGENT);
        // wrap-safe monotone >=; 0xAAAAAAAA poison reads "not ready"
        if (__all((int)(f - pub) >= 0)) break;
      }
      if (lane == 0)
        __hip_atomic_store(&ready, pub, __ATOMIC_RELAXED,
                           __HIP_MEMORY_SCOPE_WORKGROUP);
    } else {
      while ((int)(__hip_atomic_load(&ready, __ATOMIC_RELAXED,
                                     __HIP_MEMORY_SCOPE_WORKGROUP) - pub) < 0) {
      }
    }
  };

  for (int g = 0; g < NG; ++g) {
    // ---- Chebyshev coefficients: J_k(|z|), downward Miller in fp64 ----
    const float  th = theta[g];
    const double z  = (double)th * (double)SCALE;
    const double az = fmax(fabs(z), 1e-6);
    const float  sg = (th < 0.f) ? -1.f : 1.f;      // J_k(z)=sg^k J_k(|z|)

    double bv[19];
    bv[18] = 1e-30;
    bv[17] = (36.0 / az) * 1e-30;
    #pragma unroll
    for (int k = 17; k >= 1; --k)
      bv[k - 1] = (2.0 * (double)k / az) * bv[k] - bv[k + 1];
    double S = bv[0];
    #pragma unroll
    for (int k = 2; k <= 18; k += 2) S += 2.0 * bv[k];
    const double invS = 1.0 / S;

    // coeffs to float REGISTERS (constant indices only from here on)
    float jc[KMAX + 2];
    #pragma unroll
    for (int k = 0; k <= KMAX + 1; ++k) jc[k] = (float)(bv[k] * invS);

    int m = KMAX; bool found = false;
    #pragma unroll
    for (int k = 1; k <= KMAX; ++k) {
      if (!found && (double)(k + 1) > az &&
          fabs(bv[k + 1] * invS) < (double)CTOL) { m = k; found = true; }
    }
    // m identical on every wave/block -> uniform phase count

    float accr[RPW], acci[RPW];
    float wm1r[RPW], wm1i[RPW], wm2r[RPW], wm2i[RPW];
    #pragma unroll
    for (int rr = 0; rr < RPW; ++rr) {
      accr[rr] = jc[0] * pr[rr]; acci[rr] = jc[0] * pi[rr];
      wm1r[rr] = pr[rr];         wm1i[rr] = pi[rr];
      wm2r[rr] = 0.f;            wm2i[rr] = 0.f;
    }

    #pragma unroll
    for (int k = 1; k <= KMAX; ++k) {               // fully unrolled
      if (k > m) break;

      // ---- consume full w_{k-1} ----
      float vr[16], vi[16];
      if (g == 0 && k == 1) {
        // psi_0 rebuilt locally: no publish/wait phase needed
        #pragma unroll
        for (int p = 0; p < 16; ++p) {
          vr[p] = feat[p * 64 + lane] * inv;
          vi[p] = 0.f;
        }
      } else {
        wait_all();
        const u64* vsrc = (pub & 1) ? vbuf1 : vbuf0;  // buffer of phase pub
        #pragma unroll
        for (int p = 0; p < 16; ++p) {
          f2u x;
          x.u = __hip_atomic_load(vsrc + p * 64 + lane,
                                  __ATOMIC_RELAXED, __HIP_MEMORY_SCOPE_AGENT);
          vr[p] = x.f.x; vi[p] = x.f.y;
        }
      }

      // ---- y = G * w_{k-1} (own rows) ----
      float yr[RPW] = {0, 0, 0, 0}, yi[RPW] = {0, 0, 0, 0};
      #pragma unroll
      for (int p = 0; p < 16; ++p) {
        #pragma unroll
        for (int rr = 0; rr < RPW; ++rr) {
          yr[rr] = fmaf(a[rr][p], vr[p], yr[rr]);
          yi[rr] = fmaf(a[rr][p], vi[p], yi[rr]);
        }
      }
      #pragma unroll
      for (int mm = 1; mm < 64; mm <<= 1) {
        #pragma unroll
        for (int rr = 0; rr < RPW; ++rr) {
          yr[rr] += __shfl_xor(yr[rr], mm);
          yi[rr] += __shfl_xor(yi[rr], mm);
        }
      }

      // ---- w_k = (k==1) ? xh*w_0 : 2*xh*w_{k-1} - w_{k-2}  (own rows) ----
      float wkr[RPW], wki[RPW];
      #pragma unroll
      for (int rr = 0; rr < RPW; ++rr) {
        const float ur = yr[rr] * INVSCALE;
        const float ui = yi[rr] * INVSCALE;
        wkr[rr] = (k == 1) ? ur : fmaf(2.f, ur, -wm2r[rr]);
        wki[rr] = (k == 1) ? ui : fmaf(2.f, ui, -wm2i[rr]);
      }

      const bool last = (k == m);
      if (!last) publish(wkr, wki);   // stores fly before the tail VALU below

      // ---- acc += c_k * w_k,  c_k = 2*(-i*sg)^k * J_k(|z|) ----
      {
        const float j2  = 2.f * jc[k];              // register (constant k)
        const float sj2 = sg * j2;
        if ((k & 3) == 0) {
          #pragma unroll
          for (int rr = 0; rr < RPW; ++rr) {
            accr[rr] = fmaf(j2, wkr[rr], accr[rr]);
            acci[rr] = fmaf(j2, wki[rr], acci[rr]);
          }
        } else if ((k & 3) == 1) {
          #pragma unroll
          for (int rr = 0; rr < RPW; ++rr) {
            accr[rr] = fmaf( sj2, wki[rr], accr[rr]);
            acci[rr] = fmaf(-sj2, wkr[rr], acci[rr]);
          }
        } else if ((k & 3) == 2) {
          #pragma unroll
          for (int rr = 0; rr < RPW; ++rr) {
            accr[rr] = fmaf(-j2, wkr[rr], accr[rr]);
            acci[rr] = fmaf(-j2, wki[rr], acci[rr]);
          }
        } else {
          #pragma unroll
          for (int rr = 0; rr < RPW; ++rr) {
            accr[rr] = fmaf(-sj2, wki[rr], accr[rr]);
            acci[rr] = fmaf( sj2, wkr[rr], acci[rr]);
          }
        }
      }

      if (last) {
        if (g < NG - 1) {
          publish(accr, acci);                      // psi_{g+1}
          // next gate's G rows (single burst, R10-style): drains during the
          // next wait_all spin, off the critical consume path.
          const float* Gg = gens + (size_t)(g + 1) * DIM * DIM;
          #pragma unroll
          for (int rr = 0; rr < RPW; ++rr) {
            const float* Gr = Gg + (size_t)(rowbase + rr) * DIM;
            #pragma unroll
            for (int p = 0; p < 16; ++p) a[rr][p] = Gr[p * 64 + lane];
          }
        }
      } else {
        #pragma unroll
        for (int rr = 0; rr < RPW; ++rr) {
          wm2r[rr] = wm1r[rr]; wm2i[rr] = wm1i[rr];
          wm1r[rr] = wkr[rr];  wm1i[rr] = wki[rr];
        }
      }
    }
    #pragma unroll
    for (int rr = 0; rr < RPW; ++rr) { pr[rr] = accr[rr]; pi[rr] = acci[rr]; }
  }

  {
    float o = pr[0] * pr[0] + pi[0] * pi[0];
    if (lane == 1) o = pr[1] * pr[1] + pi[1] * pi[1];
    if (lane == 2) o = pr[2] * pr[2] + pi[2] * pi[2];
    if (lane == 3) o = pr[3] * pr[3] + pi[3] * pi[3];
    if (lane < RPW) out[rowbase + lane] = o;
  }
}

extern "C" void kernel_launch(void* const* d_in, const int* in_sizes, int n_in,
                              void* d_out, int out_size, void* d_ws, size_t ws_size,
                              hipStream_t stream) {
  const float* feat  = (const float*)d_in[0];
  const float* theta = (const float*)d_in[1];
  const float* gens  = (const float*)d_in[2];
  float* out = (float*)d_out;

  // layout: flags 64 x 64B (4KB) | vbuf0 (8KB) | vbuf1 (8KB)
  // no memset: wrap-safe compare treats the 0xAA poison as "not ready"
  unsigned* flags = (unsigned*)d_ws;
  u64* vbuf0 = (u64*)((char*)d_ws + 4096);
  u64* vbuf1 = (u64*)((char*)d_ws + 4096 + DIM * sizeof(u64));

  qsim_kernel<<<dim3(NBLK), dim3(TPB), 0, stream>>>(
      feat, theta, gens, out, vbuf0, vbuf1, flags);
}

// Round 14
// 164.517 us; speedup vs baseline: 1.1537x; 1.0139x over previous
//
#include <hip/hip_runtime.h>

#define DIM   1024
#define NG    8
#define NBLK  64
#define TPB   512                 // 8 waves/block
#define WAVES (TPB / 64)
#define RPW   2                   // rows per wave: NBLK*WAVES*RPW = 1024
#define ROWS_PER_BLK (WAVES * RPW)
#define SCALE    1.45f            // upper bound on spectral radius (semicircle ~1.414)
#define INVSCALE (1.0f / SCALE)
#define CTOL  5e-3f               // frozen: measured absmax 9.16e-5 vs 1.40e-4 threshold
#define KMAX  12
#define FSTRIDE 16                // flags padded to 64B (16 u32) each

typedef unsigned long long u64;
union f2u { float2 f; u64 u; };

// FINAL (R10 verbatim — measured optimum across all swept axes):
//  - NBLK 64 / TPB 512 / RPW 2  (sweeps: 32/64/128 blocks; 256/512 TPB)
//  - Chebyshev expansion of exp(-i z G/SCALE): ~23 total matvec phases
//    (Taylor needed 47), coeffs J_k by fp64 downward Miller, in registers.
//  - publish: per-wave agent-scope stores -> s_waitcnt(0) -> LDS atomicAdd
//    aggregation -> one release flag store per block (64 padded lines).
//  - wait: wave 0 polls all 64 flags with one 64-lane load; LDS wake word
//    for sibling waves. ~3.2us/phase, the measured floor over 6 mechanisms.
//  - G prefetch: single burst after the gate's last publish; drains inside
//    the next wait_all spin (smoothed per-phase prefetch regressed: vmcnt
//    strict ordering puts it on the consume's critical path).
//  - 0xAA-poison-safe wrap compares -> no workspace memset dispatch.
// Cost model (fitted R2..R13): t = 3.2us * phases + ~30us fixed; this
// kernel sits at the model floor (~103us kernel time). Latency-bound by
// 23 sequential grid-wide dependencies, not HBM (2%) or VALU (6%).

__global__ __launch_bounds__(TPB) void qsim_kernel(
    const float* __restrict__ feat,
    const float* __restrict__ theta,
    const float* __restrict__ gens,
    float*       __restrict__ out,
    u64*         __restrict__ vbuf0,
    u64*         __restrict__ vbuf1,
    unsigned*    __restrict__ flags)
{
  const int tid  = threadIdx.x;
  const int lane = tid & 63;
  const int wid  = tid >> 6;                       // 0..7
  const int bid  = blockIdx.x;
  const int rowbase = bid * ROWS_PER_BLK + wid * RPW;

  __shared__ float red[WAVES];
  __shared__ unsigned wdone;                       // monotone publish counter
  __shared__ unsigned ready;                       // monotone wake word

  // ---- gate-0 G rows first: HBM latency overlaps the norm phase ----
  float a[RPW][16];
  #pragma unroll
  for (int rr = 0; rr < RPW; ++rr) {
    const float* Gr = gens + (size_t)(rowbase + rr) * DIM;
    #pragma unroll
    for (int p = 0; p < 16; ++p) a[rr][p] = Gr[p * 64 + lane];
  }

  if (tid == 0) { wdone = 0; ready = 0; }
  {
    float f0 = feat[tid], f1 = feat[tid + TPB];
    float s = f0 * f0 + f1 * f1;
    #pragma unroll
    for (int mm = 1; mm < 64; mm <<= 1) s += __shfl_xor(s, mm);
    if (lane == 0) red[wid] = s;
  }
  __syncthreads();                                  // init only
  float tot = 0.f;
  #pragma unroll
  for (int i = 0; i < WAVES; ++i) tot += red[i];
  const float inv = 1.0f / sqrtf(tot);

  float pr[RPW], pi[RPW];
  #pragma unroll
  for (int rr = 0; rr < RPW; ++rr) {
    pr[rr] = feat[rowbase + rr] * inv;
    pi[rr] = 0.f;
  }

  unsigned pub = 0;   // completed publishes (lock-stepped across all waves)

  auto publish = [&](const float* xr, const float* xi) {
    float sr = xr[0], si = xi[0];
    if (lane == 1) { sr = xr[1]; si = xi[1]; }
    u64* dst = ((pub + 1) & 1) ? vbuf1 : vbuf0;
    if (lane < RPW) {
      f2u x; x.f = make_float2(sr, si);
      __hip_atomic_store(dst + rowbase + lane, x.u,
                         __ATOMIC_RELAXED, __HIP_MEMORY_SCOPE_AGENT);
    }
    __builtin_amdgcn_sched_barrier(0);
    __builtin_amdgcn_s_waitcnt(0);    // wave's data stores at the LLC now
    __builtin_amdgcn_sched_barrier(0);
    ++pub;
    if (lane == 0) {
      unsigned old = atomicAdd(&wdone, 1u);         // LDS, monotone
      if (old == WAVES * pub - 1) {                 // block's last publisher
        __hip_atomic_store(flags + bid * FSTRIDE, pub,
                           __ATOMIC_RELEASE, __HIP_MEMORY_SCOPE_AGENT);
      }
    }
  };

  auto wait_all = [&]() {
    if (wid == 0) {
      for (;;) {
        unsigned f = __hip_atomic_load(flags + lane * FSTRIDE,
                                       __ATOMIC_RELAXED,
                                       __HIP_MEMORY_SCOPE_AGENT);
        // wrap-safe monotone >=; 0xAAAAAAAA poison reads "not ready"
        if (__all((int)(f - pub) >= 0)) break;
      }
      if (lane == 0)
        __hip_atomic_store(&ready, pub, __ATOMIC_RELAXED,
                           __HIP_MEMORY_SCOPE_WORKGROUP);
    } else {
      while ((int)(__hip_atomic_load(&ready, __ATOMIC_RELAXED,
                                     __HIP_MEMORY_SCOPE_WORKGROUP) - pub) < 0) {
      }
    }
  };

  for (int g = 0; g < NG; ++g) {
    // ---- Chebyshev coefficients: J_k(|z|), downward Miller in fp64 ----
    const float  th = theta[g];
    const double z  = (double)th * (double)SCALE;
    const double az = fmax(fabs(z), 1e-6);
    const float  sg = (th < 0.f) ? -1.f : 1.f;      // J_k(z)=sg^k J_k(|z|)

    double bv[19];
    bv[18] = 1e-30;
    bv[17] = (36.0 / az) * 1e-30;
    #pragma unroll
    for (int k = 17; k >= 1; --k)
      bv[k - 1] = (2.0 * (double)k / az) * bv[k] - bv[k + 1];
    double S = bv[0];
    #pragma unroll
    for (int k = 2; k <= 18; k += 2) S += 2.0 * bv[k];
    const double invS = 1.0 / S;

    // coeffs to float REGISTERS (constant indices only from here on)
    float jc[KMAX + 2];
    #pragma unroll
    for (int k = 0; k <= KMAX + 1; ++k) jc[k] = (float)(bv[k] * invS);

    int m = KMAX; bool found = false;
    #pragma unroll
    for (int k = 1; k <= KMAX; ++k) {
      if (!found && (double)(k + 1) > az &&
          fabs(bv[k + 1] * invS) < (double)CTOL) { m = k; found = true; }
    }
    // m identical on every wave/block -> uniform phase count

    float accr[RPW], acci[RPW];
    float wm1r[RPW], wm1i[RPW], wm2r[RPW], wm2i[RPW];
    #pragma unroll
    for (int rr = 0; rr < RPW; ++rr) {
      accr[rr] = jc[0] * pr[rr]; acci[rr] = jc[0] * pi[rr];
      wm1r[rr] = pr[rr];         wm1i[rr] = pi[rr];
      wm2r[rr] = 0.f;            wm2i[rr] = 0.f;
    }

    #pragma unroll
    for (int k = 1; k <= KMAX; ++k) {               // fully unrolled
      if (k > m) break;

      // ---- consume full w_{k-1} ----
      float vr[16], vi[16];
      if (g == 0 && k == 1) {
        // psi_0 rebuilt locally: no publish/wait phase needed
        #pragma unroll
        for (int p = 0; p < 16; ++p) {
          vr[p] = feat[p * 64 + lane] * inv;
          vi[p] = 0.f;
        }
      } else {
        wait_all();
        const u64* vsrc = (pub & 1) ? vbuf1 : vbuf0;  // buffer of phase pub
        #pragma unroll
        for (int p = 0; p < 16; ++p) {
          f2u x;
          x.u = __hip_atomic_load(vsrc + p * 64 + lane,
                                  __ATOMIC_RELAXED, __HIP_MEMORY_SCOPE_AGENT);
          vr[p] = x.f.x; vi[p] = x.f.y;
        }
      }

      // ---- y = G * w_{k-1} (own rows) ----
      float yr[RPW] = {0, 0}, yi[RPW] = {0, 0};
      #pragma unroll
      for (int p = 0; p < 16; ++p) {
        #pragma unroll
        for (int rr = 0; rr < RPW; ++rr) {
          yr[rr] = fmaf(a[rr][p], vr[p], yr[rr]);
          yi[rr] = fmaf(a[rr][p], vi[p], yi[rr]);
        }
      }
      #pragma unroll
      for (int mm = 1; mm < 64; mm <<= 1) {
        #pragma unroll
        for (int rr = 0; rr < RPW; ++rr) {
          yr[rr] += __shfl_xor(yr[rr], mm);
          yi[rr] += __shfl_xor(yi[rr], mm);
        }
      }

      // ---- w_k = (k==1) ? xh*w_0 : 2*xh*w_{k-1} - w_{k-2}  (own rows) ----
      float wkr[RPW], wki[RPW];
      #pragma unroll
      for (int rr = 0; rr < RPW; ++rr) {
        const float ur = yr[rr] * INVSCALE;
        const float ui = yi[rr] * INVSCALE;
        wkr[rr] = (k == 1) ? ur : fmaf(2.f, ur, -wm2r[rr]);
        wki[rr] = (k == 1) ? ui : fmaf(2.f, ui, -wm2i[rr]);
      }

      const bool last = (k == m);
      if (!last) publish(wkr, wki);   // stores fly before the tail VALU below

      // ---- acc += c_k * w_k,  c_k = 2*(-i*sg)^k * J_k(|z|) ----
      {
        const float j2  = 2.f * jc[k];              // register (constant k)
        const float sj2 = sg * j2;
        if ((k & 3) == 0) {
          #pragma unroll
          for (int rr = 0; rr < RPW; ++rr) {
            accr[rr] = fmaf(j2, wkr[rr], accr[rr]);
            acci[rr] = fmaf(j2, wki[rr], acci[rr]);
          }
        } else if ((k & 3) == 1) {
          #pragma unroll
          for (int rr = 0; rr < RPW; ++rr) {
            accr[rr] = fmaf( sj2, wki[rr], accr[rr]);
            acci[rr] = fmaf(-sj2, wkr[rr], acci[rr]);
          }
        } else if ((k & 3) == 2) {
          #pragma unroll
          for (int rr = 0; rr < RPW; ++rr) {
            accr[rr] = fmaf(-j2, wkr[rr], accr[rr]);
            acci[rr] = fmaf(-j2, wki[rr], acci[rr]);
          }
        } else {
          #pragma unroll
          for (int rr = 0; rr < RPW; ++rr) {
            accr[rr] = fmaf(-sj2, wki[rr], accr[rr]);
            acci[rr] = fmaf( sj2, wkr[rr], acci[rr]);
          }
        }
      }

      if (last) {
        if (g < NG - 1) {
          publish(accr, acci);                      // psi_{g+1}
          // next gate's G rows (single burst): drains during the next
          // wait_all spin, off the critical consume path.
          const float* Gg = gens + (size_t)(g + 1) * DIM * DIM;
          #pragma unroll
          for (int rr = 0; rr < RPW; ++rr) {
            const float* Gr = Gg + (size_t)(rowbase + rr) * DIM;
            #pragma unroll
            for (int p = 0; p < 16; ++p) a[rr][p] = Gr[p * 64 + lane];
          }
        }
      } else {
        #pragma unroll
        for (int rr = 0; rr < RPW; ++rr) {
          wm2r[rr] = wm1r[rr]; wm2i[rr] = wm1i[rr];
          wm1r[rr] = wkr[rr];  wm1i[rr] = wki[rr];
        }
      }
    }
    #pragma unroll
    for (int rr = 0; rr < RPW; ++rr) { pr[rr] = accr[rr]; pi[rr] = acci[rr]; }
  }

  {
    float o = pr[0] * pr[0] + pi[0] * pi[0];
    if (lane == 1) o = pr[1] * pr[1] + pi[1] * pi[1];
    if (lane < RPW) out[rowbase + lane] = o;
  }
}

extern "C" void kernel_launch(void* const* d_in, const int* in_sizes, int n_in,
                              void* d_out, int out_size, void* d_ws, size_t ws_size,
                              hipStream_t stream) {
  const float* feat  = (const float*)d_in[0];
  const float* theta = (const float*)d_in[1];
  const float* gens  = (const float*)d_in[2];
  float* out = (float*)d_out;

  // layout: flags 64 x 64B (4KB) | vbuf0 (8KB) | vbuf1 (8KB)
  // no memset: wrap-safe compare treats the 0xAA poison as "not ready"
  unsigned* flags = (unsigned*)d_ws;
  u64* vbuf0 = (u64*)((char*)d_ws + 4096);
  u64* vbuf1 = (u64*)((char*)d_ws + 4096 + DIM * sizeof(u64));

  qsim_kernel<<<dim3(NBLK), dim3(TPB), 0, stream>>>(
      feat, theta, gens, out, vbuf0, vbuf1, flags);
}